// Round 7
// baseline (179.035 us; speedup 1.0000x reference)
//
#include <hip/hip_runtime.h>

// Problem constants (fixed by the reference):
//   TOTAL_NODES = 262144, NUM_GRAPHS = 1024, MAX_NODES = 512, D = 256
#define NUM_GRAPHS 1024
#define MAX_NODES  512
#define DIM        256
#define D4         (DIM / 4)          // 64 float4 per row (1 KB) = one wave-load

typedef float f4 __attribute__((ext_vector_type(4)));

// ---------------------------------------------------------------------------
// ONE WAVE PER GRAPH: 256 blocks x 256 threads = 1024 waves = 4 waves/CU —
// the occupancy regime where the harness fill sustains 6.7 TB/s. Each wave
// owns one contiguous 512 KB output region (graph g) and one contiguous
// <=256 KB emb region, halving stream count vs 1-block/graph (2048 streams
// total) and quadrupling per-stream run length — targeting DRAM row-buffer
// locality, the one variable not yet isolated (instruction mix, metadata,
// and CU balance are all proven non-factors: 4 variants, same 4.7 TB/s).
//
// Metadata: lanes 0/1 run lower_bound(g)/lower_bound(g+1) in lockstep (all
// lanes execute, key = g + (lane&1), no divergence), then __shfl broadcast.
// No LDS, no __syncthreads, single kernel.
// ---------------------------------------------------------------------------
__global__ void __launch_bounds__(256)
scatter_states_kernel(const f4* __restrict__ emb,
                      const int* __restrict__ bidx32, int n,
                      f4* __restrict__ out, float* __restrict__ mask) {
    const int lane = threadIdx.x & 63;
    const int g    = (blockIdx.x * blockDim.x + threadIdx.x) >> 6;  // 0..1023

    // int64 detect: little-endian int64 values < 2^31 => int32 view at index
    // n-1 is a hi-word == 0; int32 => it's the max graph id (nonzero here).
    const bool is64 = (bidx32[n - 1] == 0);

    // Wave-lockstep binary search; lane k (k in {0,1}) finds lower_bound(g+k).
    const int key = g + (lane & 1);
    int lo = 0, hi = n;
    while (lo < hi) {
        int mid = (lo + hi) >> 1;
        int v = is64 ? bidx32[2 * mid] : bidx32[mid];
        if (v < key) lo = mid + 1; else hi = mid;
    }
    const int s = __shfl(lo, 0, 64);
    const int e = __shfl(lo, 1, 64);
    const int c = e - s;                    // rows of graph g (<= 512)

    // Contiguous per-wave streams: read rows [s, s+c), write rows g*512..+512.
    const f4* wemb = emb + (size_t)s * D4 + lane;
    f4*       wout = out + (size_t)g * MAX_NODES * D4 + lane;

    int it = 0;
#pragma unroll 8
    for (; it < c; ++it)                    // copy phase (~256 KB)
        wout[it * D4] = wemb[it * D4];
    const f4 z = (f4)(0.f);
#pragma unroll 8
    for (; it < MAX_NODES; ++it)            // zero-fill phase (~256 KB)
        wout[it * D4] = z;

    // enc_mask: 512 f32 per graph, 8 per lane.
    float* mg = mask + (size_t)g * MAX_NODES;
#pragma unroll
    for (int k = 0; k < 8; ++k) {
        const int slot = k * 64 + lane;
        mg[slot] = (slot < c) ? 1.0f : 0.0f;
    }
}

extern "C" void kernel_launch(void* const* d_in, const int* in_sizes, int n_in,
                              void* d_out, int out_size, void* d_ws, size_t ws_size,
                              hipStream_t stream) {
    const float* node_emb = (const float*)d_in[0];
    const int*   bidx32   = (const int*)d_in[1];   // int32 view; kernel detects int64
    const int    n        = in_sizes[1];           // 262144

    float* mask = (float*)d_out + (size_t)NUM_GRAPHS * MAX_NODES * DIM;
    scatter_states_kernel<<<NUM_GRAPHS / 4, 256, 0, stream>>>(
        (const f4*)node_emb, bidx32, n, (f4*)d_out, mask);
}